// Round 1
// baseline (183.730 us; speedup 1.0000x reference)
//
#include <hip/hip_runtime.h>
#include <math.h>

// YOLO loss: pred/target (N,14,14,30) fp32 -> scalar.
// Memory-bound reduction; each thread handles 2 cells (240B aligned -> float4).

#define SGRID 14
#define NCLS 20
constexpr float STEPF  = 1.0f / 14.0f;
constexpr float EPSF   = 1e-7f;
constexpr float L_COORD = 5.0f;
constexpr float L_NOOBJ = 0.5f;

__device__ __forceinline__ float waveSum(float v) {
#pragma unroll
    for (int o = 32; o > 0; o >>= 1) v += __shfl_down(v, o);
    return v;
}

__global__ __launch_bounds__(256) void yolo_main(const float* __restrict__ pred,
                                                 const float* __restrict__ targ,
                                                 float* __restrict__ acc,
                                                 int nThreads) {
    int tid = blockIdx.x * blockDim.x + threadIdx.x;
    if (tid >= nThreads) return;

    // Load 2 cells = 60 floats per input, as 15 float4 each (16B aligned: 240B/thread).
    float pv[60], tv[60];
    const float4* p4 = reinterpret_cast<const float4*>(pred) + (size_t)tid * 15;
    const float4* t4 = reinterpret_cast<const float4*>(targ) + (size_t)tid * 15;
#pragma unroll
    for (int k = 0; k < 15; ++k) {
        float4 a = p4[k];
        float4 b = t4[k];
        pv[4 * k + 0] = a.x; pv[4 * k + 1] = a.y; pv[4 * k + 2] = a.z; pv[4 * k + 3] = a.w;
        tv[4 * k + 0] = b.x; tv[4 * k + 1] = b.y; tv[4 * k + 2] = b.z; tv[4 * k + 3] = b.w;
    }

    float s_obj = 0.f, s_noobj = 0.f, s_bbox = 0.f, s_nobj = 0.f, s_cls = 0.f, s_sm = 0.f;

#pragma unroll
    for (int cc = 0; cc < 2; ++cc) {
        const float* p = pv + cc * 30;
        const float* t = tv + cc * 30;
        int cell = tid * 2 + cc;                 // layout (n, jy, ix)
        float ix = (float)(cell % SGRID);
        float jy = (float)((cell / SGRID) % SGRID);

        // ---- paired IOU on cell-converted boxes (drives argmax only) ----
        float iouP[2];
#pragma unroll
        for (int b = 0; b < 2; ++b) {
            const float* pb = p + 5 * b;
            const float* tb = t + 5 * b;
            float px = fmaxf((pb[0] + ix) * STEPF - pb[2] * 0.5f, 0.f);
            float py = fmaxf((pb[1] + jy) * STEPF - pb[3] * 0.5f, 0.f);
            float pw = fmaxf(pb[2], 0.f), ph = fmaxf(pb[3], 0.f);
            float tx = fmaxf((tb[0] + ix) * STEPF - tb[2] * 0.5f, 0.f);
            float ty = fmaxf((tb[1] + jy) * STEPF - tb[3] * 0.5f, 0.f);
            float tw = fmaxf(tb[2], 0.f), th = fmaxf(tb[3], 0.f);
            float iw = pw + tw - (fmaxf(px + pw, tx + tw) - fminf(px, tx));
            float ih = ph + th - (fmaxf(py + ph, ty + th) - fminf(py, ty));
            float inter = fmaxf(iw, 0.f) * fmaxf(ih, 0.f);
            float uni = pw * ph + tw * th - inter + EPSF;
            iouP[b] = inter / uni;
        }
        int maxi = (iouP[1] > iouP[0]) ? 1 : 0;   // jnp.argmax: ties -> 0
        bool sig = t[9] > 0.f;                    // target box1 conf

#pragma unroll
        for (int b = 0; b < 2; ++b) {
            const float* pb = p + 5 * b;
            const float* tb = t + 5 * b;
            bool om = tb[4] > 0.f;
            bool kp = (!sig) || (b == maxi);
            float f = (om && kp) ? 1.f : 0.f;

            float d = pb[4] - tb[4];
            float d2 = d * d;
            s_obj   += f * d2;
            s_noobj += (1.f - f) * d2;

            // ---- DIoU on raw xywh -> xyxy ----
            float px1 = pb[0] - pb[2] * 0.5f, py1 = pb[1] - pb[3] * 0.5f;
            float px2 = pb[0] + pb[2] * 0.5f, py2 = pb[1] + pb[3] * 0.5f;
            float tx1 = tb[0] - tb[2] * 0.5f, ty1 = tb[1] - tb[3] * 0.5f;
            float tx2 = tb[0] + tb[2] * 0.5f, ty2 = tb[1] + tb[3] * 0.5f;

            float xi1 = fmaxf(px1, tx1), yi1 = fmaxf(py1, ty1);
            float xi2 = fminf(px2, tx2), yi2 = fminf(py2, ty2);
            float inter = fmaxf(xi2 - xi1, 0.f) * fmaxf(yi2 - yi1, 0.f);
            float a1 = fmaxf(px2 - px1, 0.f) * fmaxf(py2 - py1, 0.f);
            float a2 = fmaxf(tx2 - tx1, 0.f) * fmaxf(ty2 - ty1, 0.f);
            float iou = fmaxf(inter / (a1 + a2 - inter + EPSF), EPSF);

            float pcx = (px1 + px2) * 0.5f, pcy = (py1 + py2) * 0.5f;
            float tcx = (tx1 + tx2) * 0.5f, tcy = (ty1 + ty2) * 0.5f;
            float cd = (pcx - tcx) * (pcx - tcx) + (pcy - tcy) * (pcy - tcy);
            float ex1 = fminf(px1, tx1), ey1 = fminf(py1, ty1);
            float ex2 = fmaxf(px2, tx2), ey2 = fmaxf(py2, ty2);
            float diag = (ex2 - ex1) * (ex2 - ex1) + (ey2 - ey1) * (ey2 - ey1) + EPSF;
            float diou = 1.f - sqrtf(iou) + cd / diag;

            s_bbox += f * diou;
            s_nobj += f;
        }

        // ---- focal class loss ----
        float fs = 0.f;
#pragma unroll
        for (int k = 0; k < NCLS; ++k) {
            float ce = p[10 + k] - t[10 + k];
            ce *= ce;
            float pt = __expf(-ce);
            pt = fminf(fmaxf(pt, EPSF), 1.0f);
            float om1 = 1.f - pt;
            fs += om1 * om1 * ce;
        }
        float smv = sig ? 1.f : 0.f;
        s_cls += smv * fs;
        s_sm  += smv;
    }

    // ---- reduce: wave shuffle -> LDS across 4 waves -> 6 atomics/block ----
    float r[6] = { s_obj, s_noobj, s_bbox, s_nobj, s_cls, s_sm };
#pragma unroll
    for (int q = 0; q < 6; ++q) r[q] = waveSum(r[q]);

    __shared__ float red[4][6];
    int lane = threadIdx.x & 63;
    int wv   = threadIdx.x >> 6;
    if (lane == 0) {
#pragma unroll
        for (int q = 0; q < 6; ++q) red[wv][q] = r[q];
    }
    __syncthreads();
    if (threadIdx.x == 0) {
#pragma unroll
        for (int q = 0; q < 6; ++q) {
            float a = red[0][q] + red[1][q] + red[2][q] + red[3][q];
            atomicAdd(&acc[q], a);
        }
    }
}

__global__ void yolo_final(const float* __restrict__ acc, float* __restrict__ out, float invN) {
    float obj   = acc[0];
    float noobj = acc[1];
    float bboxS = acc[2];
    float nObj  = acc[3];
    float clsS  = acc[4];
    float smS   = acc[5];

    float bbox_loss = (nObj > 0.f) ? (bboxS / fmaxf(nObj, 1.f)) : 0.f;
    float nCls = smS * (float)NCLS;
    float class_loss = (nCls > 0.f) ? (clsS / fmaxf(nCls, 1.f)) : 0.f;
    float total = obj + L_NOOBJ * noobj + L_COORD * bbox_loss + class_loss;
    out[0] = total * invN;
}

extern "C" void kernel_launch(void* const* d_in, const int* in_sizes, int n_in,
                              void* d_out, int out_size, void* d_ws, size_t ws_size,
                              hipStream_t stream) {
    const float* pred = (const float*)d_in[0];
    const float* targ = (const float*)d_in[1];
    float* out = (float*)d_out;
    float* acc = (float*)d_ws;

    int N = in_sizes[0] / (SGRID * SGRID * 30);   // 4096
    int totalCells = N * SGRID * SGRID;           // 802816
    int nThreads = totalCells / 2;                // 2 cells/thread (even: S*S=196)
    int blocks = (nThreads + 255) / 256;

    hipMemsetAsync(acc, 0, 6 * sizeof(float), stream);
    yolo_main<<<blocks, 256, 0, stream>>>(pred, targ, acc, nThreads);
    yolo_final<<<1, 1, 0, stream>>>(acc, out, 1.0f / (float)N);
}